// Round 6
// baseline (1004.818 us; speedup 1.0000x reference)
//
#include <hip/hip_runtime.h>

#define B_ 64
#define N_ 196
#define C_ 768
#define H_ 16
#define DFF_ 3072
#define M_ (B_ * N_)  // 12544

typedef float f32x4 __attribute__((ext_vector_type(4)));
typedef __bf16 bf16x8 __attribute__((ext_vector_type(8)));
typedef unsigned short u16;
typedef unsigned short u16x8 __attribute__((ext_vector_type(8)));

__device__ __forceinline__ u16 f2bf(float f) {
  unsigned u = __float_as_uint(f);
  unsigned r = (u + 0x7FFFu + ((u >> 16) & 1u)) >> 16;  // RTNE
  return (u16)r;
}
__device__ __forceinline__ float bf2f(u16 h) {
  return __uint_as_float(((unsigned)h) << 16);
}

// async global->LDS, 16B per lane; LDS base must be wave-uniform (HW: base + lane*16)
__device__ __forceinline__ void gload_lds16(const u16* g, u16* l) {
  typedef const __attribute__((address_space(1))) void gp_t;
  typedef __attribute__((address_space(3))) void lp_t;
  __builtin_amdgcn_global_load_lds((gp_t*)g, (lp_t*)l, 16, 0, 0);
}

// ---------------- diagnostic sentinel fill (ws_size guard path) ----------------
__global__ __launch_bounds__(256) void fill_sentinel(float* __restrict__ out, int n) {
  for (int i = blockIdx.x * 256 + threadIdx.x; i < n; i += gridDim.x * 256)
    out[i] = 12345.0f;
}

// ---------------- f32 -> bf16 weight conversion (x4 vectorized) ----------------
__global__ __launch_bounds__(256) void f2b4(const float4* __restrict__ in,
                                            ushort4* __restrict__ out, int n4) {
  for (int i = blockIdx.x * 256 + threadIdx.x; i < n4; i += gridDim.x * 256) {
    float4 v = in[i];
    ushort4 o;
    o.x = f2bf(v.x); o.y = f2bf(v.y); o.z = f2bf(v.z); o.w = f2bf(v.w);
    out[i] = o;
  }
}

// ---------------- LayerNorm over rows of 768: f32 in -> bf16 out ----------------
__global__ __launch_bounds__(256) void ln_rows(const float* __restrict__ x,
                                               const float* __restrict__ w,
                                               const float* __restrict__ b,
                                               u16* __restrict__ out) {
  const int row = blockIdx.x;
  const int t = threadIdx.x;
  const float* xr = x + (size_t)row * C_;
  float v0 = xr[t], v1 = xr[t + 256], v2 = xr[t + 512];
  float s = v0 + v1 + v2;
  float s2 = v0 * v0 + v1 * v1 + v2 * v2;
#pragma unroll
  for (int o = 32; o; o >>= 1) { s += __shfl_xor(s, o); s2 += __shfl_xor(s2, o); }
  __shared__ float rbuf[8];
  const int wid = t >> 6;
  if ((t & 63) == 0) { rbuf[wid] = s; rbuf[wid + 4] = s2; }
  __syncthreads();
  s = rbuf[0] + rbuf[1] + rbuf[2] + rbuf[3];
  s2 = rbuf[4] + rbuf[5] + rbuf[6] + rbuf[7];
  const float mu = s * (1.f / C_);
  const float inv = rsqrtf(s2 * (1.f / C_) - mu * mu + 1e-5f);
  u16* orow = out + (size_t)row * C_;
  orow[t]       = f2bf((v0 - mu) * inv * w[t]       + b[t]);
  orow[t + 256] = f2bf((v1 - mu) * inv * w[t + 256] + b[t + 256]);
  orow[t + 512] = f2bf((v2 - mu) * inv * w[t + 512] + b[t + 512]);
}

// ---------------- positional softmax: [H,N,N] fp32, input-independent of x ----------------
__global__ __launch_bounds__(64) void pos_softmax(const float* __restrict__ pos_w,
                                                  const float* __restrict__ pos_b,
                                                  float* __restrict__ pos) {
  const int i = blockIdx.x;  // 0..195
  const int h = blockIdx.y;  // 0..15
  const int lane = threadIdx.x;
  const float w0 = pos_w[h * 3], w1 = pos_w[h * 3 + 1], w2 = pos_w[h * 3 + 2];
  const float bb = pos_b[h];
  const int iy = i / 14, ix = i % 14;
  float lg[4];
#pragma unroll
  for (int c = 0; c < 4; ++c) {
    const int j = lane + c * 64;
    if (j < N_) {
      const int jy = j / 14, jx = j % 14;
      const float dx = (float)(jx - ix), dy = (float)(jy - iy);
      lg[c] = dx * w0 + dy * w1 + (dx * dx + dy * dy) * w2 + bb;
    } else lg[c] = -3.4e38f;
  }
  float mx = fmaxf(fmaxf(lg[0], lg[1]), fmaxf(lg[2], lg[3]));
#pragma unroll
  for (int o = 32; o; o >>= 1) mx = fmaxf(mx, __shfl_xor(mx, o));
  float sum = 0.f;
#pragma unroll
  for (int c = 0; c < 4; ++c) {
    lg[c] = (lane + c * 64 < N_) ? expf(lg[c] - mx) : 0.f;
    sum += lg[c];
  }
#pragma unroll
  for (int o = 32; o; o >>= 1) sum += __shfl_xor(sum, o);
  const float inv = 1.f / sum;
  float* prow = pos + ((size_t)h * N_ + i) * N_;
#pragma unroll
  for (int c = 0; c < 4; ++c) {
    const int j = lane + c * 64;
    if (j < N_) prow[j] = lg[c] * inv;
  }
}

// ---------------- bf16 MFMA GEMM: C[M,Nn] = A[M,K] @ Bw[Nn,K]^T ----------------
// 128x128 tile, 4 waves (2x2 of 64x64), BK=64.
// m97 structure: global_load_lds width-16 staging into LINEAR LDS (rule #21:
// neither side swizzled). 1KB chunk per wave-instruction = 8 rows; lane l ->
// row chunk*8+(l>>3), cols (l&7)*8..+7, matching HW's base+lane*16B write.
// EPI 0: store bf16.  EPI 1: f32 = acc + bias[col] + res[row,col].  EPI 2: bf16 gelu(acc+bias).
#define BM 128
#define BN 128
#define BK 64

template <int EPI>
__global__ __launch_bounds__(256, 2) void gemm_bt(
    const u16* __restrict__ A, const u16* __restrict__ Bw, void* __restrict__ Cout,
    const float* __restrict__ bias, const float* __restrict__ res,
    int M, int Nn, int K) {
  __shared__ __align__(16) u16 lA[BM * BK];
  __shared__ __align__(16) u16 lB[BN * BK];
  const int t = threadIdx.x;
  const int lane = t & 63;
  const int wid = t >> 6;
  const int wr = wid >> 1, wc = wid & 1;
  const int brow = blockIdx.y * BM;
  const int bcol = blockIdx.x * BN;
  const int r16 = lane & 15;  // fragment row/col within 16
  const int kg = lane >> 4;   // k-group 0..3

  const int srow = lane >> 3;        // staging: row within 8-row chunk
  const int scol = (lane & 7) * 8;   // staging: col element offset

  f32x4 acc[4][4] = {};

  for (int k0 = 0; k0 < K; k0 += BK) {
    __syncthreads();  // previous compute done reading LDS
#pragma unroll
    for (int i = 0; i < 4; ++i) {
      const int c = wid * 4 + i;      // chunk 0..15 (1KB each)
      const int row = c * 8 + srow;   // 0..127
      gload_lds16(&A[(size_t)(brow + row) * K + k0 + scol], &lA[c * 512]);
      gload_lds16(&Bw[(size_t)(bcol + row) * K + k0 + scol], &lB[c * 512]);
    }
    __syncthreads();  // barrier drains vmcnt -> LDS ready
#pragma unroll
    for (int kk = 0; kk < 2; ++kk) {
      bf16x8 af[4], bfr[4];
#pragma unroll
      for (int m = 0; m < 4; ++m)
        af[m] = *reinterpret_cast<const bf16x8*>(
            &lA[(wr * 64 + m * 16 + r16) * BK + (kk * 4 + kg) * 8]);
#pragma unroll
      for (int n = 0; n < 4; ++n)
        bfr[n] = *reinterpret_cast<const bf16x8*>(
            &lB[(wc * 64 + n * 16 + r16) * BK + (kk * 4 + kg) * 8]);
#pragma unroll
      for (int m = 0; m < 4; ++m)
#pragma unroll
        for (int n = 0; n < 4; ++n)
          acc[m][n] = __builtin_amdgcn_mfma_f32_16x16x32_bf16(af[m], bfr[n], acc[m][n], 0, 0, 0);
    }
  }

#pragma unroll
  for (int m = 0; m < 4; ++m) {
#pragma unroll
    for (int n = 0; n < 4; ++n) {
#pragma unroll
      for (int r = 0; r < 4; ++r) {
        const int row = brow + wr * 64 + m * 16 + kg * 4 + r;
        const int col = bcol + wc * 64 + n * 16 + r16;
        const float v = acc[m][n][r];
        if (EPI == 0) {
          ((u16*)Cout)[(size_t)row * Nn + col] = f2bf(v);
        } else if (EPI == 1) {
          ((float*)Cout)[(size_t)row * Nn + col] = v + bias[col] + res[(size_t)row * Nn + col];
        } else {
          const float u = v + bias[col];
          ((u16*)Cout)[(size_t)row * Nn + col] =
              f2bf(0.5f * u * (1.f + erff(u * 0.70710678118654752f)));
        }
      }
    }
  }
}

// ---------------- fused GPSA attention (fp32 compute, bf16 I/O) ----------------
// one block per (b,h); K,V in LDS; wave-per-row softmax; lane-per-d PV
__global__ __launch_bounds__(256) void attn_fused(const u16* __restrict__ qkv,
                                                  const float* __restrict__ pos,
                                                  const float* __restrict__ gating,
                                                  u16* __restrict__ out) {
  const int bh = blockIdx.x;
  const int b = bh >> 4, h = bh & 15;
  __shared__ __align__(16) u16 sK[N_][56];  // pad 48->56 to break bank conflicts
  __shared__ __align__(16) u16 sV[N_][56];
  __shared__ float sAttn[4][N_];
  const int t = threadIdx.x, lane = t & 63, w = t >> 6;

  for (int idx = t; idx < N_ * 6; idx += 256) {
    const int j = idx / 6, c8 = idx % 6;
    const size_t base = ((size_t)(b * N_ + j)) * 2304 + h * 48 + c8 * 8;
    *reinterpret_cast<uint4*>(&sK[j][c8 * 8]) = *reinterpret_cast<const uint4*>(&qkv[base + 768]);
    *reinterpret_cast<uint4*>(&sV[j][c8 * 8]) = *reinterpret_cast<const uint4*>(&qkv[base + 1536]);
  }
  __syncthreads();
  const float sig = 1.f / (1.f + expf(-gating[h]));
  const float scale = 0.14433756729740643f;  // 48^-0.5

  for (int i0 = 0; i0 < N_; i0 += 4) {
    const int i = i0 + w;  // each wave owns one row; 196 = 49*4 exactly
    // Q row straight from global (wave-uniform address -> broadcast)
    const u16* qrow = qkv + ((size_t)(b * N_ + i)) * 2304 + h * 48;
    u16x8 q[6];
#pragma unroll
    for (int c8 = 0; c8 < 6; ++c8) q[c8] = *reinterpret_cast<const u16x8*>(qrow + c8 * 8);

    float sc[4] = {0.f, 0.f, 0.f, 0.f};
#pragma unroll
    for (int c8 = 0; c8 < 6; ++c8) {
      float qf[8];
#pragma unroll
      for (int e = 0; e < 8; ++e) qf[e] = bf2f(q[c8][e]);
#pragma unroll
      for (int c = 0; c < 4; ++c) {
        const int j = lane + c * 64;
        if (j < N_) {
          const u16x8 kc = *reinterpret_cast<const u16x8*>(&sK[j][c8 * 8]);
#pragma unroll
          for (int e = 0; e < 8; ++e) sc[c] = fmaf(qf[e], bf2f(kc[e]), sc[c]);
        }
      }
    }
#pragma unroll
    for (int c = 0; c < 4; ++c) sc[c] *= scale;
    float mx = -3.4e38f;
#pragma unroll
    for (int c = 0; c < 4; ++c)
      if (lane + c * 64 < N_) mx = fmaxf(mx, sc[c]);
#pragma unroll
    for (int o = 32; o; o >>= 1) mx = fmaxf(mx, __shfl_xor(mx, o));
    float p[4], sum = 0.f;
#pragma unroll
    for (int c = 0; c < 4; ++c) {
      p[c] = (lane + c * 64 < N_) ? expf(sc[c] - mx) : 0.f;
      sum += p[c];
    }
#pragma unroll
    for (int o = 32; o; o >>= 1) sum += __shfl_xor(sum, o);
    const float isum = 1.f / sum;
    const float* prow = pos + ((size_t)h * N_ + i) * N_;
    float rs = 0.f;
#pragma unroll
    for (int c = 0; c < 4; ++c) {
      const int j = lane + c * 64;
      if (j < N_) { p[c] = (1.f - sig) * p[c] * isum + sig * prow[j]; rs += p[c]; }
    }
#pragma unroll
    for (int o = 32; o; o >>= 1) rs += __shfl_xor(rs, o);
    const float irs = 1.f / rs;
#pragma unroll
    for (int c = 0; c < 4; ++c) {
      const int j = lane + c * 64;
      if (j < N_) sAttn[w][j] = p[c] * irs;
    }
    __syncthreads();  // cross-lane LDS handoff within/between waves
    if (lane < 48) {
      float o = 0.f;
#pragma unroll 4
      for (int j = 0; j < N_; ++j) o = fmaf(sAttn[w][j], bf2f(sV[j][lane]), o);
      out[((size_t)(b * N_ + i)) * C_ + h * 48 + lane] = f2bf(o);
    }
    __syncthreads();  // protect sAttn before next iteration overwrites
  }
}

// ---------------- launch ----------------
extern "C" void kernel_launch(void* const* d_in, const int* in_sizes, int n_in,
                              void* d_out, int out_size, void* d_ws, size_t ws_size,
                              hipStream_t stream) {
  // ---- ws_size guard: never touch d_ws beyond its real size. If the harness
  // gave us less scratch than the pipeline needs, emit a clean sentinel output
  // (absmax ~1.2e4) instead of faulting the GPU. ws_size is constant across
  // calls, so this branch is deterministic and graph-capture-safe.
  const size_t WS_NEEDED = 151487488;
  if (ws_size < WS_NEEDED) {
    fill_sentinel<<<512, 256, 0, stream>>>((float*)d_out, out_size);
    return;
  }

  const float* x      = (const float*)d_in[0];
  const float* n1w    = (const float*)d_in[1];
  const float* n1b    = (const float*)d_in[2];
  const float* qk_w   = (const float*)d_in[3];
  const float* v_w    = (const float*)d_in[4];
  const float* pos_w  = (const float*)d_in[5];
  const float* pos_b  = (const float*)d_in[6];
  const float* gating = (const float*)d_in[7];
  const float* proj_w = (const float*)d_in[8];
  const float* proj_b = (const float*)d_in[9];
  const float* n2w    = (const float*)d_in[10];
  const float* n2b    = (const float*)d_in[11];
  const float* fc1_w  = (const float*)d_in[12];
  const float* fc1_b  = (const float*)d_in[13];
  const float* fc2_w  = (const float*)d_in[14];
  const float* fc2_b  = (const float*)d_in[15];

  char* ws = (char*)d_ws;
  // workspace layout (bytes); total = 151,487,488
  // xn2 overlays xn (xn dead after the qkv GEMM; xn2 written after proj GEMM).
  // hbuf overlays qkv+attno (both dead once fc1 runs).
  u16*   xn    = (u16*)(ws + 0);          // 12544x768  bf16  19.27MB (slot shared w/ xn2)
  u16*   xn2   = (u16*)(ws + 0);          //   "      "   — same slot, later liveness
  u16*   wqkv  = (u16*)(ws + 19267584);   // 2304x768   bf16   3.54MB
  u16*   wproj = (u16*)(ws + 22806528);   // 768x768    bf16   1.18MB
  u16*   wfc1  = (u16*)(ws + 23986176);   // 3072x768   bf16   4.72MB
  u16*   wfc2  = (u16*)(ws + 28704768);   // 768x3072   bf16   4.72MB
  float* pos   = (float*)(ws + 33423360); // 16x196x196 f32    2.46MB
  float* x1    = (float*)(ws + 35881984); // 12544x768  f32   38.54MB -> ends 74417152
  u16*   qkv   = (u16*)(ws + 74417152);   // 12544x2304 bf16  57.80MB -> ends 132219904
  u16*   attno = (u16*)(ws + 132219904);  // 12544x768  bf16  19.27MB -> ends 151487488
  u16*   hbuf  = (u16*)(ws + 74417152);   // 12544x3072 bf16  77.07MB (overlays qkv+attno)

  f2b4<<<512, 256, 0, stream>>>((const float4*)qk_w,   (ushort4*)wqkv,                (1536 * 768) / 4);
  f2b4<<<512, 256, 0, stream>>>((const float4*)v_w,    (ushort4*)(wqkv + 1536 * 768), (768 * 768) / 4);
  f2b4<<<512, 256, 0, stream>>>((const float4*)proj_w, (ushort4*)wproj,               (768 * 768) / 4);
  f2b4<<<512, 256, 0, stream>>>((const float4*)fc1_w,  (ushort4*)wfc1,                (3072 * 768) / 4);
  f2b4<<<512, 256, 0, stream>>>((const float4*)fc2_w,  (ushort4*)wfc2,                (768 * 3072) / 4);
  ln_rows<<<M_, 256, 0, stream>>>(x, n1w, n1b, xn);
  pos_softmax<<<dim3(196, 16), 64, 0, stream>>>(pos_w, pos_b, pos);
  gemm_bt<0><<<dim3(2304 / BN, M_ / BM), 256, 0, stream>>>(xn, wqkv, qkv, nullptr, nullptr, M_, 2304, 768);
  attn_fused<<<B_ * H_, 256, 0, stream>>>(qkv, pos, gating, attno);
  gemm_bt<1><<<dim3(768 / BN, M_ / BM), 256, 0, stream>>>(attno, wproj, x1, proj_b, x, M_, 768, 768);
  ln_rows<<<M_, 256, 0, stream>>>(x1, n2w, n2b, xn2);
  gemm_bt<2><<<dim3(3072 / BN, M_ / BM), 256, 0, stream>>>(xn2, wfc1, hbuf, fc1_b, nullptr, M_, 3072, 768);
  gemm_bt<1><<<dim3(768 / BN, M_ / BM), 256, 0, stream>>>(hbuf, wfc2, (float*)d_out, fc2_b, x1, M_, 768, 3072);
}

// Round 7
// 523.975 us; speedup vs baseline: 1.9177x; 1.9177x over previous
//
#include <hip/hip_runtime.h>

#define B_ 64
#define N_ 196
#define C_ 768
#define H_ 16
#define DFF_ 3072
#define M_ (B_ * N_)  // 12544

typedef float f32x4 __attribute__((ext_vector_type(4)));
typedef __bf16 bf16x8 __attribute__((ext_vector_type(8)));
typedef unsigned short u16;
typedef unsigned short u16x8 __attribute__((ext_vector_type(8)));

__device__ __forceinline__ u16 f2bf(float f) {
  unsigned u = __float_as_uint(f);
  unsigned r = (u + 0x7FFFu + ((u >> 16) & 1u)) >> 16;  // RTNE
  return (u16)r;
}
__device__ __forceinline__ float bf2f(u16 h) {
  return __uint_as_float(((unsigned)h) << 16);
}

// async global->LDS, 16B per lane; LDS base must be wave-uniform (HW: base + lane*16)
__device__ __forceinline__ void gload_lds16(const u16* g, u16* l) {
  typedef const __attribute__((address_space(1))) void gp_t;
  typedef __attribute__((address_space(3))) void lp_t;
  __builtin_amdgcn_global_load_lds((gp_t*)g, (lp_t*)l, 16, 0, 0);
}

// ---------------- diagnostic sentinel fill (ws_size guard path) ----------------
__global__ __launch_bounds__(256) void fill_sentinel(float* __restrict__ out, int n) {
  for (int i = blockIdx.x * 256 + threadIdx.x; i < n; i += gridDim.x * 256)
    out[i] = 12345.0f;
}

// ---------------- f32 -> bf16 weight conversion (x4 vectorized) ----------------
__global__ __launch_bounds__(256) void f2b4(const float4* __restrict__ in,
                                            ushort4* __restrict__ out, int n4) {
  for (int i = blockIdx.x * 256 + threadIdx.x; i < n4; i += gridDim.x * 256) {
    float4 v = in[i];
    ushort4 o;
    o.x = f2bf(v.x); o.y = f2bf(v.y); o.z = f2bf(v.z); o.w = f2bf(v.w);
    out[i] = o;
  }
}

// ---------------- LayerNorm over rows of 768: f32 in -> bf16 out ----------------
__global__ __launch_bounds__(256) void ln_rows(const float* __restrict__ x,
                                               const float* __restrict__ w,
                                               const float* __restrict__ b,
                                               u16* __restrict__ out) {
  const int row = blockIdx.x;
  const int t = threadIdx.x;
  const float* xr = x + (size_t)row * C_;
  float v0 = xr[t], v1 = xr[t + 256], v2 = xr[t + 512];
  float s = v0 + v1 + v2;
  float s2 = v0 * v0 + v1 * v1 + v2 * v2;
#pragma unroll
  for (int o = 32; o; o >>= 1) { s += __shfl_xor(s, o); s2 += __shfl_xor(s2, o); }
  __shared__ float rbuf[8];
  const int wid = t >> 6;
  if ((t & 63) == 0) { rbuf[wid] = s; rbuf[wid + 4] = s2; }
  __syncthreads();
  s = rbuf[0] + rbuf[1] + rbuf[2] + rbuf[3];
  s2 = rbuf[4] + rbuf[5] + rbuf[6] + rbuf[7];
  const float mu = s * (1.f / C_);
  const float inv = rsqrtf(s2 * (1.f / C_) - mu * mu + 1e-5f);
  u16* orow = out + (size_t)row * C_;
  orow[t]       = f2bf((v0 - mu) * inv * w[t]       + b[t]);
  orow[t + 256] = f2bf((v1 - mu) * inv * w[t + 256] + b[t + 256]);
  orow[t + 512] = f2bf((v2 - mu) * inv * w[t + 512] + b[t + 512]);
}

// ---------------- positional softmax: [H,N,N] fp32, input-independent of x ----------------
__global__ __launch_bounds__(64) void pos_softmax(const float* __restrict__ pos_w,
                                                  const float* __restrict__ pos_b,
                                                  float* __restrict__ pos) {
  const int i = blockIdx.x;  // 0..195
  const int h = blockIdx.y;  // 0..15
  const int lane = threadIdx.x;
  const float w0 = pos_w[h * 3], w1 = pos_w[h * 3 + 1], w2 = pos_w[h * 3 + 2];
  const float bb = pos_b[h];
  const int iy = i / 14, ix = i % 14;
  float lg[4];
#pragma unroll
  for (int c = 0; c < 4; ++c) {
    const int j = lane + c * 64;
    if (j < N_) {
      const int jy = j / 14, jx = j % 14;
      const float dx = (float)(jx - ix), dy = (float)(jy - iy);
      lg[c] = dx * w0 + dy * w1 + (dx * dx + dy * dy) * w2 + bb;
    } else lg[c] = -3.4e38f;
  }
  float mx = fmaxf(fmaxf(lg[0], lg[1]), fmaxf(lg[2], lg[3]));
#pragma unroll
  for (int o = 32; o; o >>= 1) mx = fmaxf(mx, __shfl_xor(mx, o));
  float sum = 0.f;
#pragma unroll
  for (int c = 0; c < 4; ++c) {
    lg[c] = (lane + c * 64 < N_) ? expf(lg[c] - mx) : 0.f;
    sum += lg[c];
  }
#pragma unroll
  for (int o = 32; o; o >>= 1) sum += __shfl_xor(sum, o);
  const float inv = 1.f / sum;
  float* prow = pos + ((size_t)h * N_ + i) * N_;
#pragma unroll
  for (int c = 0; c < 4; ++c) {
    const int j = lane + c * 64;
    if (j < N_) prow[j] = lg[c] * inv;
  }
}

// ---------------- bf16 MFMA GEMM: C[M,Nn] = A[M,K] @ Bw[Nn,K]^T ----------------
// 128x128 tile, 4 waves (2x2 of 64x64), BK=64.
// m97 structure: global_load_lds width-16 staging into LINEAR LDS (rule #21:
// neither side swizzled). 1KB chunk per wave-instruction = 8 rows; lane l ->
// row chunk*8+(l>>3), cols (l&7)*8..+7, matching HW's base+lane*16B write.
// EPI 0: store bf16.  EPI 1: f32 = acc + bias[col] + res[row,col].  EPI 2: bf16 gelu(acc+bias).
#define BM 128
#define BN 128
#define BK 64

template <int EPI>
__global__ __launch_bounds__(256, 2) void gemm_bt(
    const u16* __restrict__ A, const u16* __restrict__ Bw, void* __restrict__ Cout,
    const float* __restrict__ bias, const float* __restrict__ res,
    int M, int Nn, int K) {
  __shared__ __align__(16) u16 lA[BM * BK];
  __shared__ __align__(16) u16 lB[BN * BK];
  const int t = threadIdx.x;
  const int lane = t & 63;
  const int wid = t >> 6;
  const int wr = wid >> 1, wc = wid & 1;
  const int brow = blockIdx.y * BM;
  const int bcol = blockIdx.x * BN;
  const int r16 = lane & 15;  // fragment row/col within 16
  const int kg = lane >> 4;   // k-group 0..3

  const int srow = lane >> 3;        // staging: row within 8-row chunk
  const int scol = (lane & 7) * 8;   // staging: col element offset

  f32x4 acc[4][4] = {};

  for (int k0 = 0; k0 < K; k0 += BK) {
    __syncthreads();  // previous compute done reading LDS
#pragma unroll
    for (int i = 0; i < 4; ++i) {
      const int c = wid * 4 + i;      // chunk 0..15 (1KB each)
      const int row = c * 8 + srow;   // 0..127
      gload_lds16(&A[(size_t)(brow + row) * K + k0 + scol], &lA[c * 512]);
      gload_lds16(&Bw[(size_t)(bcol + row) * K + k0 + scol], &lB[c * 512]);
    }
    __syncthreads();  // barrier drains vmcnt -> LDS ready
#pragma unroll
    for (int kk = 0; kk < 2; ++kk) {
      bf16x8 af[4], bfr[4];
#pragma unroll
      for (int m = 0; m < 4; ++m)
        af[m] = *reinterpret_cast<const bf16x8*>(
            &lA[(wr * 64 + m * 16 + r16) * BK + (kk * 4 + kg) * 8]);
#pragma unroll
      for (int n = 0; n < 4; ++n)
        bfr[n] = *reinterpret_cast<const bf16x8*>(
            &lB[(wc * 64 + n * 16 + r16) * BK + (kk * 4 + kg) * 8]);
#pragma unroll
      for (int m = 0; m < 4; ++m)
#pragma unroll
        for (int n = 0; n < 4; ++n)
          acc[m][n] = __builtin_amdgcn_mfma_f32_16x16x32_bf16(af[m], bfr[n], acc[m][n], 0, 0, 0);
    }
  }

#pragma unroll
  for (int m = 0; m < 4; ++m) {
#pragma unroll
    for (int n = 0; n < 4; ++n) {
#pragma unroll
      for (int r = 0; r < 4; ++r) {
        const int row = brow + wr * 64 + m * 16 + kg * 4 + r;
        const int col = bcol + wc * 64 + n * 16 + r16;
        const float v = acc[m][n][r];
        if (EPI == 0) {
          ((u16*)Cout)[(size_t)row * Nn + col] = f2bf(v);
        } else if (EPI == 1) {
          ((float*)Cout)[(size_t)row * Nn + col] = v + bias[col] + res[(size_t)row * Nn + col];
        } else {
          const float u = v + bias[col];
          ((u16*)Cout)[(size_t)row * Nn + col] =
              f2bf(0.5f * u * (1.f + erff(u * 0.70710678118654752f)));
        }
      }
    }
  }
}

// ---------------- MFMA GPSA attention ----------------
// One block per (b,h), 4 waves. Tiles: 13 mt row-tiles of 16 (208, pad>=196),
// 13 nt col-tiles, K=48 padded to 64 via zero A-frags.
// S = Q@K^T: A-frag = Q rows (global), B-frag = K rows (global, L1-cached).
// Softmax + pos-mix + renorm in C-layout registers (row = 4*(lane>>4)+reg,
// col = lane&15; row-reduce = shfl_xor 1/2/4/8 within 16-lane group).
// PV: P stripe [16][PSTR] bf16 per wave in LDS (A-frag), V^T [48][PSTR] in LDS
// (B-frag). PSTR=232: stride 464B -> 2-way bank aliasing (free, m136).
// Single __syncthreads (after V^T staging); no cross-wave P sharing.
#define PSTR 232

__global__ __launch_bounds__(256, 2) void attn_mfma(const u16* __restrict__ qkv,
                                                    const float* __restrict__ pos,
                                                    const float* __restrict__ gating,
                                                    u16* __restrict__ out) {
  const int bh = blockIdx.x;
  const int b = bh >> 4, h = bh & 15;
  __shared__ __align__(16) u16 VT[48][PSTR];       // V transposed, cols j (pad 0)
  __shared__ __align__(16) u16 P[4][16][PSTR];     // per-wave P stripe
  const int t = threadIdx.x, lane = t & 63, w = t >> 6;
  const int c16 = lane & 15, g = lane >> 4;

  // stage V^T: (j, c8) -> VT[c8*8+e][j]; coalesced global reads
  for (int idx = t; idx < N_ * 6; idx += 256) {
    const int j = idx / 6, c8 = idx % 6;
    const u16x8 v = *reinterpret_cast<const u16x8*>(
        &qkv[((size_t)(b * N_ + j)) * 2304 + 1536 + h * 48 + c8 * 8]);
#pragma unroll
    for (int e = 0; e < 8; ++e) VT[c8 * 8 + e][j] = v[e];
  }
  // zero pad cols 196..231 of VT (18 dwords per row)
  for (int idx = t; idx < 48 * 18; idx += 256) {
    const int d = idx / 18, q = idx % 18;
    *reinterpret_cast<unsigned*>(&VT[d][196 + q * 2]) = 0u;
  }
  // zero pad cols 196..231 of all P stripes (written cols stay < 208)
  for (int idx = t; idx < 4 * 16 * 18; idx += 256) {
    const int wv = idx / (16 * 18), rr = (idx / 18) % 16, q = idx % 18;
    *reinterpret_cast<unsigned*>(&P[wv][rr][196 + q * 2]) = 0u;
  }
  __syncthreads();

  const float sig = 1.f / (1.f + __expf(-gating[h]));
  const float scale = 0.14433756729740643f;  // 48^-0.5
  const float* poshp = pos + (size_t)h * N_ * N_;

  for (int mt = w; mt < 13; mt += 4) {
    // ---- Q A-frags (global; rows >=196 read in-ws garbage, contained to dead rows)
    bf16x8 qa0, qa1;
    {
      const int irow = mt * 16 + c16;
      const u16* qp = &qkv[((size_t)(b * N_ + irow)) * 2304 + h * 48];
      qa0 = *reinterpret_cast<const bf16x8*>(qp + g * 8);
      if (g < 2) qa1 = *reinterpret_cast<const bf16x8*>(qp + 32 + g * 8);
      else       qa1 = bf16x8{};  // zero k-pad 48..63 for ALL rows (lane-distributed)
    }

    // ---- S = Q K^T for 13 col-tiles
    f32x4 s[13];
#pragma unroll
    for (int nt = 0; nt < 13; ++nt) {
      const int jrow = nt * 16 + c16;
      const u16* kp = &qkv[((size_t)(b * N_ + jrow)) * 2304 + 768 + h * 48];
      const bf16x8 kb0 = *reinterpret_cast<const bf16x8*>(kp + g * 8);
      const bf16x8 kb1 = *reinterpret_cast<const bf16x8*>(kp + 32 + g * 8);  // k-pad nulled by qa1
      f32x4 acc = {};
      acc = __builtin_amdgcn_mfma_f32_16x16x32_bf16(qa0, kb0, acc, 0, 0, 0);
      acc = __builtin_amdgcn_mfma_f32_16x16x32_bf16(qa1, kb1, acc, 0, 0, 0);
      s[nt] = acc;
    }

    // ---- patch softmax (rows 4g+r), mask cols j>=196
    float mx[4] = {-3.4e38f, -3.4e38f, -3.4e38f, -3.4e38f};
#pragma unroll
    for (int nt = 0; nt < 13; ++nt)
#pragma unroll
      for (int r = 0; r < 4; ++r) {
        float v = s[nt][r];
        if (nt == 12 && c16 >= 4) v = -3.4e38f;  // j = 192+c16 >= 196
        s[nt][r] = v;
        mx[r] = fmaxf(mx[r], v);
      }
#pragma unroll
    for (int r = 0; r < 4; ++r)
#pragma unroll
      for (int o = 1; o < 16; o <<= 1) mx[r] = fmaxf(mx[r], __shfl_xor(mx[r], o));

    float sum[4] = {0.f, 0.f, 0.f, 0.f};
#pragma unroll
    for (int nt = 0; nt < 13; ++nt)
#pragma unroll
      for (int r = 0; r < 4; ++r) {
        const float p = __expf((s[nt][r] - mx[r]) * scale);
        s[nt][r] = p;
        sum[r] += p;
      }
#pragma unroll
    for (int r = 0; r < 4; ++r) {
#pragma unroll
      for (int o = 1; o < 16; o <<= 1) sum[r] += __shfl_xor(sum[r], o);
      sum[r] = (1.f - sig) / sum[r];  // fold (1-sig) into patch normalizer
    }

    // ---- attn = (1-sig)*patch + sig*pos; renormalize by row total
    float tot[4] = {0.f, 0.f, 0.f, 0.f};
    const int i0g = mt * 16 + 4 * g;
#pragma unroll
    for (int nt = 0; nt < 13; ++nt) {
      const int j = nt * 16 + c16;
#pragma unroll
      for (int r = 0; r < 4; ++r) {
        const int i = i0g + r;
        float pv = 0.f;
        if (i < N_ && j < N_) pv = poshp[(size_t)i * N_ + j];
        float a = s[nt][r] * sum[r] + sig * pv;
        if (j >= N_) a = 0.f;  // pad cols exactly zero (valid rows)
        s[nt][r] = a;
        tot[r] += a;
      }
    }
#pragma unroll
    for (int r = 0; r < 4; ++r) {
#pragma unroll
      for (int o = 1; o < 16; o <<= 1) tot[r] += __shfl_xor(tot[r], o);
      tot[r] = 1.f / tot[r];
    }

    // ---- write P stripe (bf16); same-wave LDS write->read, lgkmcnt ordered
#pragma unroll
    for (int nt = 0; nt < 13; ++nt)
#pragma unroll
      for (int r = 0; r < 4; ++r)
        P[w][4 * g + r][nt * 16 + c16] = f2bf(s[nt][r] * tot[r]);

    // ---- O = P V : A-frag = P stripe, B-frag = V^T
    f32x4 oacc[3] = {};
#pragma unroll
    for (int kk2 = 0; kk2 < 7; ++kk2) {
      const bf16x8 pa = *reinterpret_cast<const bf16x8*>(&P[w][c16][kk2 * 32 + g * 8]);
#pragma unroll
      for (int dt = 0; dt < 3; ++dt) {
        const bf16x8 vb = *reinterpret_cast<const bf16x8*>(&VT[dt * 16 + c16][kk2 * 32 + g * 8]);
        oacc[dt] = __builtin_amdgcn_mfma_f32_16x16x32_bf16(pa, vb, oacc[dt], 0, 0, 0);
      }
    }

    // ---- store (guard dead rows)
#pragma unroll
    for (int dt = 0; dt < 3; ++dt)
#pragma unroll
      for (int r = 0; r < 4; ++r) {
        const int i = i0g + r;
        if (i < N_)
          out[((size_t)(b * N_ + i)) * C_ + h * 48 + dt * 16 + c16] = f2bf(oacc[dt][r]);
      }
  }
}

// ---------------- launch ----------------
extern "C" void kernel_launch(void* const* d_in, const int* in_sizes, int n_in,
                              void* d_out, int out_size, void* d_ws, size_t ws_size,
                              hipStream_t stream) {
  // ---- ws_size guard (deterministic, graph-capture-safe)
  const size_t WS_NEEDED = 151487488;
  if (ws_size < WS_NEEDED) {
    fill_sentinel<<<512, 256, 0, stream>>>((float*)d_out, out_size);
    return;
  }

  const float* x      = (const float*)d_in[0];
  const float* n1w    = (const float*)d_in[1];
  const float* n1b    = (const float*)d_in[2];
  const float* qk_w   = (const float*)d_in[3];
  const float* v_w    = (const float*)d_in[4];
  const float* pos_w  = (const float*)d_in[5];
  const float* pos_b  = (const float*)d_in[6];
  const float* gating = (const float*)d_in[7];
  const float* proj_w = (const float*)d_in[8];
  const float* proj_b = (const float*)d_in[9];
  const float* n2w    = (const float*)d_in[10];
  const float* n2b    = (const float*)d_in[11];
  const float* fc1_w  = (const float*)d_in[12];
  const float* fc1_b  = (const float*)d_in[13];
  const float* fc2_w  = (const float*)d_in[14];
  const float* fc2_b  = (const float*)d_in[15];

  char* ws = (char*)d_ws;
  // workspace layout (bytes); total = 151,487,488
  // xn2 overlays xn (xn dead after qkv GEMM); hbuf overlays qkv+attno.
  u16*   xn    = (u16*)(ws + 0);          // 12544x768  bf16  19.27MB (shared w/ xn2)
  u16*   xn2   = (u16*)(ws + 0);
  u16*   wqkv  = (u16*)(ws + 19267584);   // 2304x768   bf16   3.54MB
  u16*   wproj = (u16*)(ws + 22806528);   // 768x768    bf16   1.18MB
  u16*   wfc1  = (u16*)(ws + 23986176);   // 3072x768   bf16   4.72MB
  u16*   wfc2  = (u16*)(ws + 28704768);   // 768x3072   bf16   4.72MB
  float* pos   = (float*)(ws + 33423360); // 16x196x196 f32    2.46MB
  float* x1    = (float*)(ws + 35881984); // 12544x768  f32   38.54MB -> ends 74417152
  u16*   qkv   = (u16*)(ws + 74417152);   // 12544x2304 bf16  57.80MB -> ends 132219904
  u16*   attno = (u16*)(ws + 132219904);  // 12544x768  bf16  19.27MB -> ends 151487488
  u16*   hbuf  = (u16*)(ws + 74417152);   // 12544x3072 bf16  77.07MB (overlays qkv+attno)

  f2b4<<<512, 256, 0, stream>>>((const float4*)qk_w,   (ushort4*)wqkv,                (1536 * 768) / 4);
  f2b4<<<512, 256, 0, stream>>>((const float4*)v_w,    (ushort4*)(wqkv + 1536 * 768), (768 * 768) / 4);
  f2b4<<<512, 256, 0, stream>>>((const float4*)proj_w, (ushort4*)wproj,               (768 * 768) / 4);
  f2b4<<<512, 256, 0, stream>>>((const float4*)fc1_w,  (ushort4*)wfc1,                (3072 * 768) / 4);
  f2b4<<<512, 256, 0, stream>>>((const float4*)fc2_w,  (ushort4*)wfc2,                (768 * 3072) / 4);
  ln_rows<<<M_, 256, 0, stream>>>(x, n1w, n1b, xn);
  pos_softmax<<<dim3(196, 16), 64, 0, stream>>>(pos_w, pos_b, pos);
  gemm_bt<0><<<dim3(2304 / BN, M_ / BM), 256, 0, stream>>>(xn, wqkv, qkv, nullptr, nullptr, M_, 2304, 768);
  attn_mfma<<<B_ * H_, 256, 0, stream>>>(qkv, pos, gating, attno);
  gemm_bt<1><<<dim3(768 / BN, M_ / BM), 256, 0, stream>>>(attno, wproj, x1, proj_b, x, M_, 768, 768);
  ln_rows<<<M_, 256, 0, stream>>>(x1, n2w, n2b, xn2);
  gemm_bt<2><<<dim3(3072 / BN, M_ / BM), 256, 0, stream>>>(xn2, wfc1, hbuf, fc1_b, nullptr, M_, 3072, 768);
  gemm_bt<1><<<dim3(768 / BN, M_ / BM), 256, 0, stream>>>(hbuf, wfc2, (float*)d_out, fc2_b, x1, M_, 768, 3072);
}

// Round 8
// 506.410 us; speedup vs baseline: 1.9842x; 1.0347x over previous
//
#include <hip/hip_runtime.h>

#define B_ 64
#define N_ 196
#define C_ 768
#define H_ 16
#define DFF_ 3072
#define M_ (B_ * N_)  // 12544

typedef float f32x4 __attribute__((ext_vector_type(4)));
typedef __bf16 bf16x8 __attribute__((ext_vector_type(8)));
typedef unsigned short u16;
typedef unsigned short u16x8 __attribute__((ext_vector_type(8)));

__device__ __forceinline__ u16 f2bf(float f) {
  unsigned u = __float_as_uint(f);
  unsigned r = (u + 0x7FFFu + ((u >> 16) & 1u)) >> 16;  // RTNE
  return (u16)r;
}
__device__ __forceinline__ float bf2f(u16 h) {
  return __uint_as_float(((unsigned)h) << 16);
}

// async global->LDS, 16B per lane; LDS base must be wave-uniform (HW: base + lane*16)
__device__ __forceinline__ void gload_lds16(const u16* g, u16* l) {
  typedef const __attribute__((address_space(1))) void gp_t;
  typedef __attribute__((address_space(3))) void lp_t;
  __builtin_amdgcn_global_load_lds((gp_t*)g, (lp_t*)l, 16, 0, 0);
}

// ---------------- diagnostic sentinel fill (ws_size guard path) ----------------
__global__ __launch_bounds__(256) void fill_sentinel(float* __restrict__ out, int n) {
  for (int i = blockIdx.x * 256 + threadIdx.x; i < n; i += gridDim.x * 256)
    out[i] = 12345.0f;
}

// ---------------- f32 -> bf16 weight conversion (x4 vectorized) ----------------
__global__ __launch_bounds__(256) void f2b4(const float4* __restrict__ in,
                                            ushort4* __restrict__ out, int n4) {
  for (int i = blockIdx.x * 256 + threadIdx.x; i < n4; i += gridDim.x * 256) {
    float4 v = in[i];
    ushort4 o;
    o.x = f2bf(v.x); o.y = f2bf(v.y); o.z = f2bf(v.z); o.w = f2bf(v.w);
    out[i] = o;
  }
}

// ---------------- LayerNorm over rows of 768: f32 in -> bf16 out ----------------
__global__ __launch_bounds__(256) void ln_rows(const float* __restrict__ x,
                                               const float* __restrict__ w,
                                               const float* __restrict__ b,
                                               u16* __restrict__ out) {
  const int row = blockIdx.x;
  const int t = threadIdx.x;
  const float* xr = x + (size_t)row * C_;
  float v0 = xr[t], v1 = xr[t + 256], v2 = xr[t + 512];
  float s = v0 + v1 + v2;
  float s2 = v0 * v0 + v1 * v1 + v2 * v2;
#pragma unroll
  for (int o = 32; o; o >>= 1) { s += __shfl_xor(s, o); s2 += __shfl_xor(s2, o); }
  __shared__ float rbuf[8];
  const int wid = t >> 6;
  if ((t & 63) == 0) { rbuf[wid] = s; rbuf[wid + 4] = s2; }
  __syncthreads();
  s = rbuf[0] + rbuf[1] + rbuf[2] + rbuf[3];
  s2 = rbuf[4] + rbuf[5] + rbuf[6] + rbuf[7];
  const float mu = s * (1.f / C_);
  const float inv = rsqrtf(s2 * (1.f / C_) - mu * mu + 1e-5f);
  u16* orow = out + (size_t)row * C_;
  orow[t]       = f2bf((v0 - mu) * inv * w[t]       + b[t]);
  orow[t + 256] = f2bf((v1 - mu) * inv * w[t + 256] + b[t + 256]);
  orow[t + 512] = f2bf((v2 - mu) * inv * w[t + 512] + b[t + 512]);
}

// ---------------- positional softmax: [H,N,N] fp32, input-independent of x ----------------
__global__ __launch_bounds__(64) void pos_softmax(const float* __restrict__ pos_w,
                                                  const float* __restrict__ pos_b,
                                                  float* __restrict__ pos) {
  const int i = blockIdx.x;  // 0..195
  const int h = blockIdx.y;  // 0..15
  const int lane = threadIdx.x;
  const float w0 = pos_w[h * 3], w1 = pos_w[h * 3 + 1], w2 = pos_w[h * 3 + 2];
  const float bb = pos_b[h];
  const int iy = i / 14, ix = i % 14;
  float lg[4];
#pragma unroll
  for (int c = 0; c < 4; ++c) {
    const int j = lane + c * 64;
    if (j < N_) {
      const int jy = j / 14, jx = j % 14;
      const float dx = (float)(jx - ix), dy = (float)(jy - iy);
      lg[c] = dx * w0 + dy * w1 + (dx * dx + dy * dy) * w2 + bb;
    } else lg[c] = -3.4e38f;
  }
  float mx = fmaxf(fmaxf(lg[0], lg[1]), fmaxf(lg[2], lg[3]));
#pragma unroll
  for (int o = 32; o; o >>= 1) mx = fmaxf(mx, __shfl_xor(mx, o));
  float sum = 0.f;
#pragma unroll
  for (int c = 0; c < 4; ++c) {
    lg[c] = (lane + c * 64 < N_) ? expf(lg[c] - mx) : 0.f;
    sum += lg[c];
  }
#pragma unroll
  for (int o = 32; o; o >>= 1) sum += __shfl_xor(sum, o);
  const float inv = 1.f / sum;
  float* prow = pos + ((size_t)h * N_ + i) * N_;
#pragma unroll
  for (int c = 0; c < 4; ++c) {
    const int j = lane + c * 64;
    if (j < N_) prow[j] = lg[c] * inv;
  }
}

// ---------------- 256x256 8-phase bf16 MFMA GEMM: C = A[M,K] @ Bw[Nn,K]^T ----
// m201-style template: BK=64, 8 waves (2Mx4N), per-wave 128x64 output,
// 128KB LDS double-buffer, XOR-swizzled LDS via pre-swizzled global source
// (rule #21), counted vmcnt (T4), per-phase barriers (T3), setprio (T5).
// Stage schedule (derived; both invariants hold):
//   ph1: A(u+1) both halves | ph2: B0(u+2) | ph3: B1(u+2) | ph4: vmcnt(4)
//   ph5: A(u+2) both halves | ph6: B0(u+3) | ph7: B1(u+3) | ph8: vmcnt(4)
//   (last iteration: stages of tiles >= T skipped; ph4 uses vmcnt(0))
// EPI 0: bf16 store. 1: f32 acc+bias+res. 2: bf16 gelu(acc+bias).

#define DSREAD_B(TILE)                                                        \
  {                                                                           \
    const int pB = ((TILE) & 1) * 32768 + 16384 + (wc >> 1) * 8192;           \
    _Pragma("unroll") for (int fc = 0; fc < 4; ++fc) {                        \
      const int rb = (wc & 1) * 64 + fc * 16 + c16;                           \
      _Pragma("unroll") for (int ks = 0; ks < 2; ++ks)                        \
          bfr[fc][ks] = *reinterpret_cast<const bf16x8*>(                     \
              &lds[pB + rb * 64 + 8 * ((4 * ks + g) ^ (rb & 7))]);            \
    }                                                                         \
  }

#define DSREAD_A(Q, TILE)                                                     \
  {                                                                           \
    const int pA = ((TILE) & 1) * 32768 + wr * 8192;                          \
    _Pragma("unroll") for (int fr2 = 0; fr2 < 2; ++fr2) {                     \
      const int r = ((Q) * 2 + fr2) * 16 + c16;                               \
      _Pragma("unroll") for (int ks = 0; ks < 2; ++ks)                        \
          af[fr2][ks] = *reinterpret_cast<const bf16x8*>(                     \
              &lds[pA + r * 64 + 8 * ((4 * ks + g) ^ (r & 7))]);              \
    }                                                                         \
  }

#define MMAQ(Q)                                                               \
  _Pragma("unroll") for (int fr2 = 0; fr2 < 2; ++fr2)                         \
      _Pragma("unroll") for (int fc = 0; fc < 4; ++fc)                        \
          _Pragma("unroll") for (int ks = 0; ks < 2; ++ks)                    \
              acc[(Q) * 2 + fr2][fc] = __builtin_amdgcn_mfma_f32_16x16x32_bf16( \
                  af[fr2][ks], bfr[fc][ks], acc[(Q) * 2 + fr2][fc], 0, 0, 0);

#define PHASE(Q, TILE, STAGES, VMW)                                           \
  {                                                                           \
    if ((Q) == 0) DSREAD_B(TILE);                                             \
    DSREAD_A(Q, TILE);                                                        \
    STAGES;                                                                   \
    __builtin_amdgcn_s_barrier();                                             \
    asm volatile("s_waitcnt lgkmcnt(0)" ::: "memory");                        \
    __builtin_amdgcn_sched_barrier(0);                                        \
    __builtin_amdgcn_s_setprio(1);                                            \
    MMAQ(Q);                                                                  \
    __builtin_amdgcn_s_setprio(0);                                            \
    VMW;                                                                      \
    __builtin_amdgcn_s_barrier();                                             \
  }

template <int EPI>
__global__ __launch_bounds__(512, 2) void gemm256(
    const u16* __restrict__ A, const u16* __restrict__ Bw, void* __restrict__ Cout,
    const float* __restrict__ bias, const float* __restrict__ res,
    int M, int Nn, int K) {
  __shared__ __align__(16) u16 lds[65536];  // 128KB: [buf][A|B][half][128][64], swizzled
  const int t = threadIdx.x, lane = t & 63, wid = t >> 6;
  const int wr = wid >> 2, wc = wid & 3;
  const int c16 = lane & 15, g = lane >> 4;
  const int brow = blockIdx.y * 256, bcol = blockIdx.x * 256;
  const int srow = lane >> 3;                    // staging: row within 8-row chunk
  const int scol = 8 * ((lane & 7) ^ srow);      // pre-swizzled source col (elems)

  // stage one half-tile (128x64): this wave's chunks wid and wid+8 (8 rows each)
  auto stageA = [&](int tile, int h) {
    const int p = (tile & 1) * 32768 + h * 8192;
    const u16* gs = A + (size_t)(brow + h * 128 + wid * 8 + srow) * K + tile * 64 + scol;
    gload_lds16(gs, &lds[p + wid * 512]);
    gload_lds16(gs + (size_t)64 * K, &lds[p + 4096 + wid * 512]);
  };
  auto stageB = [&](int tile, int h) {
    const int p = (tile & 1) * 32768 + 16384 + h * 8192;
    const u16* gs = Bw + (size_t)(bcol + h * 128 + wid * 8 + srow) * K + tile * 64 + scol;
    gload_lds16(gs, &lds[p + wid * 512]);
    gload_lds16(gs + (size_t)64 * K, &lds[p + 4096 + wid * 512]);
  };

  f32x4 acc[8][4] = {};
  bf16x8 bfr[4][2], af[2][2];
  const int NI = K / 128;  // two K-tiles (BK=64) per iteration

  // prologue: tile0 fully + B halves of tile1; wait tile0 landed (B(1) in flight)
  stageB(0, 0); stageB(0, 1); stageA(0, 0); stageA(0, 1);
  stageB(1, 0); stageB(1, 1);
  asm volatile("s_waitcnt vmcnt(4)" ::: "memory");
  __builtin_amdgcn_s_barrier();

  for (int it = 0, u = 0; it < NI; ++it, u += 2) {
    const bool last = (it == NI - 1);
    PHASE(0, u, { stageA(u + 1, 0); stageA(u + 1, 1); }, {});
    PHASE(1, u, { if (!last) stageB(u + 2, 0); }, {});
    PHASE(2, u, { if (!last) stageB(u + 2, 1); }, {});
    PHASE(3, u, {}, {
      if (last) { asm volatile("s_waitcnt vmcnt(0)" ::: "memory"); }
      else      { asm volatile("s_waitcnt vmcnt(4)" ::: "memory"); }
    });
    PHASE(0, u + 1, { if (!last) { stageA(u + 2, 0); stageA(u + 2, 1); } }, {});
    PHASE(1, u + 1, { if (!last) stageB(u + 3, 0); }, {});
    PHASE(2, u + 1, { if (!last) stageB(u + 3, 1); }, {});
    PHASE(3, u + 1, {}, {
      if (!last) { asm volatile("s_waitcnt vmcnt(4)" ::: "memory"); }
    });
  }

  // epilogue: C/D layout row = 4*(lane>>4)+reg, col = lane&15
#pragma unroll
  for (int fr = 0; fr < 8; ++fr) {
#pragma unroll
    for (int fc = 0; fc < 4; ++fc) {
#pragma unroll
      for (int ri = 0; ri < 4; ++ri) {
        const int row = brow + wr * 128 + fr * 16 + g * 4 + ri;
        const int col = bcol + wc * 64 + fc * 16 + c16;
        const float v = acc[fr][fc][ri];
        if (EPI == 0) {
          ((u16*)Cout)[(size_t)row * Nn + col] = f2bf(v);
        } else if (EPI == 1) {
          ((float*)Cout)[(size_t)row * Nn + col] = v + bias[col] + res[(size_t)row * Nn + col];
        } else {
          const float u2 = v + bias[col];
          ((u16*)Cout)[(size_t)row * Nn + col] =
              f2bf(0.5f * u2 * (1.f + erff(u2 * 0.70710678118654752f)));
        }
      }
    }
  }
}

// ---------------- MFMA GPSA attention (unchanged from round 6) ----------------
#define PSTR 232

__global__ __launch_bounds__(256, 2) void attn_mfma(const u16* __restrict__ qkv,
                                                    const float* __restrict__ pos,
                                                    const float* __restrict__ gating,
                                                    u16* __restrict__ out) {
  const int bh = blockIdx.x;
  const int b = bh >> 4, h = bh & 15;
  __shared__ __align__(16) u16 VT[48][PSTR];
  __shared__ __align__(16) u16 P[4][16][PSTR];
  const int t = threadIdx.x, lane = t & 63, w = t >> 6;
  const int c16 = lane & 15, g = lane >> 4;

  for (int idx = t; idx < N_ * 6; idx += 256) {
    const int j = idx / 6, c8 = idx % 6;
    const u16x8 v = *reinterpret_cast<const u16x8*>(
        &qkv[((size_t)(b * N_ + j)) * 2304 + 1536 + h * 48 + c8 * 8]);
#pragma unroll
    for (int e = 0; e < 8; ++e) VT[c8 * 8 + e][j] = v[e];
  }
  for (int idx = t; idx < 48 * 18; idx += 256) {
    const int d = idx / 18, q = idx % 18;
    *reinterpret_cast<unsigned*>(&VT[d][196 + q * 2]) = 0u;
  }
  for (int idx = t; idx < 4 * 16 * 18; idx += 256) {
    const int wv = idx / (16 * 18), rr = (idx / 18) % 16, q = idx % 18;
    *reinterpret_cast<unsigned*>(&P[wv][rr][196 + q * 2]) = 0u;
  }
  __syncthreads();

  const float sig = 1.f / (1.f + __expf(-gating[h]));
  const float scale = 0.14433756729740643f;
  const float* poshp = pos + (size_t)h * N_ * N_;

  for (int mt = w; mt < 13; mt += 4) {
    bf16x8 qa0, qa1;
    {
      const int irow = mt * 16 + c16;
      const u16* qp = &qkv[((size_t)(b * N_ + irow)) * 2304 + h * 48];
      qa0 = *reinterpret_cast<const bf16x8*>(qp + g * 8);
      if (g < 2) qa1 = *reinterpret_cast<const bf16x8*>(qp + 32 + g * 8);
      else       qa1 = bf16x8{};
    }

    f32x4 s[13];
#pragma unroll
    for (int nt = 0; nt < 13; ++nt) {
      const int jrow = nt * 16 + c16;
      const u16* kp = &qkv[((size_t)(b * N_ + jrow)) * 2304 + 768 + h * 48];
      const bf16x8 kb0 = *reinterpret_cast<const bf16x8*>(kp + g * 8);
      const bf16x8 kb1 = *reinterpret_cast<const bf16x8*>(kp + 32 + g * 8);
      f32x4 acc = {};
      acc = __builtin_amdgcn_mfma_f32_16x16x32_bf16(qa0, kb0, acc, 0, 0, 0);
      acc = __builtin_amdgcn_mfma_f32_16x16x32_bf16(qa1, kb1, acc, 0, 0, 0);
      s[nt] = acc;
    }

    float mx[4] = {-3.4e38f, -3.4e38f, -3.4e38f, -3.4e38f};
#pragma unroll
    for (int nt = 0; nt < 13; ++nt)
#pragma unroll
      for (int r = 0; r < 4; ++r) {
        float v = s[nt][r];
        if (nt == 12 && c16 >= 4) v = -3.4e38f;
        s[nt][r] = v;
        mx[r] = fmaxf(mx[r], v);
      }
#pragma unroll
    for (int r = 0; r < 4; ++r)
#pragma unroll
      for (int o = 1; o < 16; o <<= 1) mx[r] = fmaxf(mx[r], __shfl_xor(mx[r], o));

    float sum[4] = {0.f, 0.f, 0.f, 0.f};
#pragma unroll
    for (int nt = 0; nt < 13; ++nt)
#pragma unroll
      for (int r = 0; r < 4; ++r) {
        const float p = __expf((s[nt][r] - mx[r]) * scale);
        s[nt][r] = p;
        sum[r] += p;
      }
#pragma unroll
    for (int r = 0; r < 4; ++r) {
#pragma unroll
      for (int o = 1; o < 16; o <<= 1) sum[r] += __shfl_xor(sum[r], o);
      sum[r] = (1.f - sig) / sum[r];
    }

    float tot[4] = {0.f, 0.f, 0.f, 0.f};
    const int i0g = mt * 16 + 4 * g;
#pragma unroll
    for (int nt = 0; nt < 13; ++nt) {
      const int j = nt * 16 + c16;
#pragma unroll
      for (int r = 0; r < 4; ++r) {
        const int i = i0g + r;
        float pv = 0.f;
        if (i < N_ && j < N_) pv = poshp[(size_t)i * N_ + j];
        float a = s[nt][r] * sum[r] + sig * pv;
        if (j >= N_) a = 0.f;
        s[nt][r] = a;
        tot[r] += a;
      }
    }
#pragma unroll
    for (int r = 0; r < 4; ++r) {
#pragma unroll
      for (int o = 1; o < 16; o <<= 1) tot[r] += __shfl_xor(tot[r], o);
      tot[r] = 1.f / tot[r];
    }

#pragma unroll
    for (int nt = 0; nt < 13; ++nt)
#pragma unroll
      for (int r = 0; r < 4; ++r)
        P[w][4 * g + r][nt * 16 + c16] = f2bf(s[nt][r] * tot[r]);

    f32x4 oacc[3] = {};
#pragma unroll
    for (int kk2 = 0; kk2 < 7; ++kk2) {
      const bf16x8 pa = *reinterpret_cast<const bf16x8*>(&P[w][c16][kk2 * 32 + g * 8]);
#pragma unroll
      for (int dt = 0; dt < 3; ++dt) {
        const bf16x8 vb = *reinterpret_cast<const bf16x8*>(&VT[dt * 16 + c16][kk2 * 32 + g * 8]);
        oacc[dt] = __builtin_amdgcn_mfma_f32_16x16x32_bf16(pa, vb, oacc[dt], 0, 0, 0);
      }
    }

#pragma unroll
    for (int dt = 0; dt < 3; ++dt)
#pragma unroll
      for (int r = 0; r < 4; ++r) {
        const int i = i0g + r;
        if (i < N_)
          out[((size_t)(b * N_ + i)) * C_ + h * 48 + dt * 16 + c16] = f2bf(oacc[dt][r]);
      }
  }
}

// ---------------- launch ----------------
extern "C" void kernel_launch(void* const* d_in, const int* in_sizes, int n_in,
                              void* d_out, int out_size, void* d_ws, size_t ws_size,
                              hipStream_t stream) {
  const size_t WS_NEEDED = 151487488;
  if (ws_size < WS_NEEDED) {
    fill_sentinel<<<512, 256, 0, stream>>>((float*)d_out, out_size);
    return;
  }

  const float* x      = (const float*)d_in[0];
  const float* n1w    = (const float*)d_in[1];
  const float* n1b    = (const float*)d_in[2];
  const float* qk_w   = (const float*)d_in[3];
  const float* v_w    = (const float*)d_in[4];
  const float* pos_w  = (const float*)d_in[5];
  const float* pos_b  = (const float*)d_in[6];
  const float* gating = (const float*)d_in[7];
  const float* proj_w = (const float*)d_in[8];
  const float* proj_b = (const float*)d_in[9];
  const float* n2w    = (const float*)d_in[10];
  const float* n2b    = (const float*)d_in[11];
  const float* fc1_w  = (const float*)d_in[12];
  const float* fc1_b  = (const float*)d_in[13];
  const float* fc2_w  = (const float*)d_in[14];
  const float* fc2_b  = (const float*)d_in[15];

  char* ws = (char*)d_ws;
  // workspace layout (bytes); total = 151,487,488
  u16*   xn    = (u16*)(ws + 0);          // 12544x768  bf16 (slot shared w/ xn2)
  u16*   xn2   = (u16*)(ws + 0);
  u16*   wqkv  = (u16*)(ws + 19267584);   // 2304x768   bf16
  u16*   wproj = (u16*)(ws + 22806528);   // 768x768    bf16
  u16*   wfc1  = (u16*)(ws + 23986176);   // 3072x768   bf16
  u16*   wfc2  = (u16*)(ws + 28704768);   // 768x3072   bf16
  float* pos   = (float*)(ws + 33423360); // 16x196x196 f32
  float* x1    = (float*)(ws + 35881984); // 12544x768  f32   -> ends 74417152
  u16*   qkv   = (u16*)(ws + 74417152);   // 12544x2304 bf16  -> ends 132219904
  u16*   attno = (u16*)(ws + 132219904);  // 12544x768  bf16  -> ends 151487488
  u16*   hbuf  = (u16*)(ws + 74417152);   // 12544x3072 bf16 (overlays qkv+attno)

  f2b4<<<512, 256, 0, stream>>>((const float4*)qk_w,   (ushort4*)wqkv,                (1536 * 768) / 4);
  f2b4<<<512, 256, 0, stream>>>((const float4*)v_w,    (ushort4*)(wqkv + 1536 * 768), (768 * 768) / 4);
  f2b4<<<512, 256, 0, stream>>>((const float4*)proj_w, (ushort4*)wproj,               (768 * 768) / 4);
  f2b4<<<512, 256, 0, stream>>>((const float4*)fc1_w,  (ushort4*)wfc1,                (3072 * 768) / 4);
  f2b4<<<512, 256, 0, stream>>>((const float4*)fc2_w,  (ushort4*)wfc2,                (768 * 3072) / 4);
  ln_rows<<<M_, 256, 0, stream>>>(x, n1w, n1b, xn);
  pos_softmax<<<dim3(196, 16), 64, 0, stream>>>(pos_w, pos_b, pos);
  gemm256<0><<<dim3(2304 / 256, M_ / 256), 512, 0, stream>>>(xn, wqkv, qkv, nullptr, nullptr, M_, 2304, 768);
  attn_mfma<<<B_ * H_, 256, 0, stream>>>(qkv, pos, gating, attno);
  gemm256<1><<<dim3(768 / 256, M_ / 256), 512, 0, stream>>>(attno, wproj, x1, proj_b, x, M_, 768, 768);
  ln_rows<<<M_, 256, 0, stream>>>(x1, n2w, n2b, xn2);
  gemm256<2><<<dim3(3072 / 256, M_ / 256), 512, 0, stream>>>(xn2, wfc1, hbuf, fc1_b, nullptr, M_, 3072, 768);
  gemm256<1><<<dim3(768 / 256, M_ / 256), 512, 0, stream>>>(hbuf, wfc2, (float*)d_out, fc2_b, x1, M_, 768, 3072);
}